// Round 10
// baseline (253.538 us; speedup 1.0000x reference)
//
#include <hip/hip_runtime.h>
#include <math.h>

#define Bv   32
#define Nv   1024
#define Dv   768
#define Cv   201
#define Kv   5
#define CKv  1005
#define BNv  32768
#define NCLS 200

// output offsets (floats)
#define OFF_CL     0
#define OFF_IPL    6400
#define OFF_LOG    38560
#define OFF_PART   32970400
#define OFF_PNEW   33003168
#define OFF_PSEUDO 33775008

typedef short bf16x8 __attribute__((ext_vector_type(8)));
typedef float f32x4  __attribute__((ext_vector_type(4)));
typedef __attribute__((address_space(1))) const unsigned int g_u32;
typedef __attribute__((address_space(3))) unsigned int l_u32;

__device__ inline unsigned short f2bf(float f) {
  unsigned u = __float_as_uint(f);
  u += 0x7fffu + ((u >> 16) & 1u);     // RNE
  return (unsigned short)(u >> 16);
}
__device__ inline float bf2f(unsigned short h) {
  return __uint_as_float(((unsigned)h) << 16);
}
// order-preserving float<->uint for atomicMax
__device__ inline unsigned fenc(float f) {
  unsigned u = __float_as_uint(f);
  return u ^ (((unsigned)((int)u >> 31)) | 0x80000000u);
}
__device__ inline float fdec(unsigned u) {
  unsigned bits = (u & 0x80000000u) ? (u ^ 0x80000000u) : ~u;
  return __uint_as_float(bits);
}

// ---------------- fused: zero (leading blocks) + row norms + bf16 split
// blocks [0, ZB): zero P_acc/present/iplU region (zn ints)
// then rows [0,BN): pt -> Ah (hi only, linear, 768 shorts/row)
// rows [BN, BN+1024): proto(pad) -> Bhl (hi|lo interleaved, 1536 shorts/row)
// rows [BN+1024, 2BN+1024): raw -> inv_raw
__global__ __launch_bounds__(256) void prep_kernel(
    const float* __restrict__ pt, const float* __restrict__ raw,
    const float* __restrict__ proto,
    unsigned short* __restrict__ Ah, unsigned short* __restrict__ Bhl,
    float* __restrict__ inv_raw, int* __restrict__ zbuf, int zn, int ZB) {
  if ((int)blockIdx.x < ZB) {
    int i = blockIdx.x * 256 + threadIdx.x;
    if (i < zn) zbuf[i] = 0;
    return;
  }
  int row = (blockIdx.x - ZB) * 4 + (threadIdx.x >> 6);
  int l   = threadIdx.x & 63;

  if (row < BNv) {                       // ---- A: hi-only
    const float* src = pt + (size_t)row * Dv;
    unsigned short* dst = Ah + (size_t)row * Dv;
    float4 v[3];
    float s = 0.f;
#pragma unroll
    for (int i = 0; i < 3; ++i) {
      v[i] = reinterpret_cast<const float4*>(src)[i * 64 + l];
      s += v[i].x * v[i].x + v[i].y * v[i].y + v[i].z * v[i].z + v[i].w * v[i].w;
    }
#pragma unroll
    for (int off = 32; off > 0; off >>= 1) s += __shfl_xor(s, off);
    float inv = 1.0f / fmaxf(sqrtf(s), 1e-12f);
#pragma unroll
    for (int i = 0; i < 3; ++i) {
      float a[4] = {v[i].x * inv, v[i].y * inv, v[i].z * inv, v[i].w * inv};
      *reinterpret_cast<ushort4*>(dst + i * 256 + 4 * l) =
          make_ushort4(f2bf(a[0]), f2bf(a[1]), f2bf(a[2]), f2bf(a[3]));
    }
    return;
  }
  if (row < BNv + 1024) {                // ---- B: hi|lo interleaved
    int rp = row - BNv;
    unsigned short* dst = Bhl + (size_t)rp * 1536;
    if (rp >= CKv) {                     // zero-fill pad rows
      ushort4 z = make_ushort4(0, 0, 0, 0);
#pragma unroll
      for (int i = 0; i < 3; ++i) {
        int db = 8 * i + (l >> 3);
        int base = db * 64 + 4 * (l & 7);
        *reinterpret_cast<ushort4*>(dst + base)      = z;
        *reinterpret_cast<ushort4*>(dst + base + 32) = z;
      }
      return;
    }
    const float* src = proto + (size_t)rp * Dv;
    float4 v[3];
    float s = 0.f;
#pragma unroll
    for (int i = 0; i < 3; ++i) {
      v[i] = reinterpret_cast<const float4*>(src)[i * 64 + l];
      s += v[i].x * v[i].x + v[i].y * v[i].y + v[i].z * v[i].z + v[i].w * v[i].w;
    }
#pragma unroll
    for (int off = 32; off > 0; off >>= 1) s += __shfl_xor(s, off);
    float inv = 1.0f / fmaxf(sqrtf(s), 1e-12f);
#pragma unroll
    for (int i = 0; i < 3; ++i) {
      float a[4] = {v[i].x * inv, v[i].y * inv, v[i].z * inv, v[i].w * inv};
      unsigned short hh[4], ll[4];
#pragma unroll
      for (int t = 0; t < 4; ++t) {
        hh[t] = f2bf(a[t]);
        ll[t] = f2bf(a[t] - bf2f(hh[t]));
      }
      int db = 8 * i + (l >> 3);
      int base = db * 64 + 4 * (l & 7);
      *reinterpret_cast<ushort4*>(dst + base)      = make_ushort4(hh[0], hh[1], hh[2], hh[3]);
      *reinterpret_cast<ushort4*>(dst + base + 32) = make_ushort4(ll[0], ll[1], ll[2], ll[3]);
    }
    return;
  }
  if (row < 2 * BNv + 1024) {            // ---- raw: norm only
    int rr = row - BNv - 1024;
    const float* src = raw + (size_t)rr * Dv;
    float s = 0.f;
#pragma unroll
    for (int i = 0; i < 3; ++i) {
      float4 v = reinterpret_cast<const float4*>(src)[i * 64 + l];
      s += v.x * v.x + v.y * v.y + v.z * v.z + v.w * v.w;
    }
#pragma unroll
    for (int off = 32; off > 0; off >>= 1) s += __shfl_xor(s, off);
    if (l == 0) inv_raw[rr] = 1.0f / fmaxf(sqrtf(s), 1e-12f);
  }
}

// ------------------------------------------------- MFMA 2-pass split GEMM
// logits[m][n] = dot(a_hi[m,:], b_hi[n,:]+b_lo[n,:]); fused col-max -> iplU
// BM=256 x BN=128, 512 thr / 8 waves (4M x 2N), BK=32 (24 tiles), dbuf LDS.
// Per tile: 4 barrier-bracketed fine phases (T3), each = {2 ds_reads (b
// quadrant) -> lgkm(0) -> setprio(1) 8 MFMA setprio(0) -> barrier}; all 4
// next-tile loads issued at tile start, counted vmcnt(4) (T4, never drain-0).
// Epilogue: PLAIN stores (NT was a 1.5x store-path throttle, fixed R9).
#define BM 256
#define BN 128
__global__ __launch_bounds__(512) void gemm_mfma_kernel(
    const unsigned short* __restrict__ Ah, const unsigned short* __restrict__ Bhl,
    float* __restrict__ Co, unsigned int* __restrict__ iplU) {
  __shared__ __align__(16) unsigned short lA[2][BM][32];   // 2 x 16 KB
  __shared__ __align__(16) unsigned short lB[2][BN][64];   // 2 x 16 KB
  const int tid  = threadIdx.x;
  const int wid  = tid >> 6;
  const int lane = tid & 63;
  const int wm = wid >> 1, wn = wid & 1;
  const int m0 = blockIdx.x * BM, n0 = blockIdx.y * BN;
  const int fr = lane & 15;
  const int q  = lane >> 4;

  f32x4 acc[4][4];
#pragma unroll
  for (int i = 0; i < 4; ++i)
#pragma unroll
    for (int j = 0; j < 4; ++j)
#pragma unroll
      for (int r = 0; r < 4; ++r) acc[i][j][r] = 0.f;

  // staging source pointers (swizzled global source, linear LDS dest).
  const int raA = wid * 16 + (lane >> 2);            // 0..127
  const int saA = (lane & 3) ^ ((raA >> 1) & 3);     // +128 preserves (row>>1)&3
  const unsigned short* srcA0 = Ah + (size_t)(m0 + raA) * Dv + saA * 8;
  const unsigned short* srcA1 = Ah + (size_t)(m0 + 128 + raA) * Dv + saA * 8;
  const int rbB = wid * 8 + (lane >> 3);             // 0..63
  const int sbB = (lane & 7) ^ (rbB & 7);            // +64 preserves row&7
  const unsigned short* srcB0 = Bhl + (size_t)(n0 + rbB) * 1536 + sbB * 8;
  const unsigned short* srcB1 = Bhl + (size_t)(n0 + 64 + rbB) * 1536 + sbB * 8;

#define STG_A0(buf, t) __builtin_amdgcn_global_load_lds((g_u32*)(srcA0 + (t) * 32), \
    (l_u32*)&lA[buf][wid * 16][0], 16, 0, 0)
#define STG_A1(buf, t) __builtin_amdgcn_global_load_lds((g_u32*)(srcA1 + (t) * 32), \
    (l_u32*)&lA[buf][128 + wid * 16][0], 16, 0, 0)
#define STG_B0(buf, t) __builtin_amdgcn_global_load_lds((g_u32*)(srcB0 + (t) * 64), \
    (l_u32*)&lB[buf][wid * 8][0], 16, 0, 0)
#define STG_B1(buf, t) __builtin_amdgcn_global_load_lds((g_u32*)(srcB1 + (t) * 64), \
    (l_u32*)&lB[buf][64 + wid * 8][0], 16, 0, 0)

  const int slotA = (q ^ ((fr >> 1) & 3)) * 8;       // const per lane
  const int shB   = (q ^ (fr & 7)) * 8;
  const int slB   = ((q + 4) ^ (fr & 7)) * 8;

  // prologue: tile 0 into buf 0 (4 loads/wave in flight)
  STG_A0(0, 0); STG_A1(0, 0); STG_B0(0, 0); STG_B1(0, 0);

#pragma unroll 2
  for (int t = 0; t < 24; ++t) {
    const int cur = t & 1;
    // issue all 4 next-tile loads, then counted wait (they stay in flight)
    if (t < 23) {
      STG_A0(cur ^ 1, t + 1); STG_A1(cur ^ 1, t + 1);
      STG_B0(cur ^ 1, t + 1); STG_B1(cur ^ 1, t + 1);
      asm volatile("s_waitcnt vmcnt(4)" ::: "memory");
    } else {
      asm volatile("s_waitcnt vmcnt(0)" ::: "memory");
    }
    __builtin_amdgcn_s_barrier();            // all waves' tile-t stage landed
    __builtin_amdgcn_sched_barrier(0);       // pin ds_reads below barrier

    bf16x8 a[4];
#pragma unroll
    for (int j = 0; j < 4; ++j) {
      // ---- phase j: ds-load subtile, fence, MFMA cluster, barrier ----
      if (j == 0) {
#pragma unroll
        for (int i = 0; i < 4; ++i)
          a[i] = *reinterpret_cast<const bf16x8*>(&lA[cur][wm * 64 + i * 16 + fr][slotA]);
      }
      const unsigned short* pb = &lB[cur][wn * 64 + j * 16 + fr][0];
      bf16x8 bh = *reinterpret_cast<const bf16x8*>(pb + shB);
      bf16x8 bl = *reinterpret_cast<const bf16x8*>(pb + slB);
      asm volatile("s_waitcnt lgkmcnt(0)" ::: "memory");
      __builtin_amdgcn_sched_barrier(0);
      __builtin_amdgcn_s_setprio(1);
#pragma unroll
      for (int i = 0; i < 4; ++i) {
        acc[i][j] = __builtin_amdgcn_mfma_f32_16x16x32_bf16(a[i], bh, acc[i][j], 0, 0, 0);
        acc[i][j] = __builtin_amdgcn_mfma_f32_16x16x32_bf16(a[i], bl, acc[i][j], 0, 0, 0);
      }
      __builtin_amdgcn_s_setprio(0);
      __builtin_amdgcn_sched_barrier(0);
      __builtin_amdgcn_s_barrier();          // phase boundary (wave lockstep)
      __builtin_amdgcn_sched_barrier(0);
    }
  }
#undef STG_A0
#undef STG_A1
#undef STG_B0
#undef STG_B1

  // epilogue: plain store (L2 write-combining) + fused column-max for ipl
  const int b_img = m0 >> 10;
  const int mbase = m0 + wm * 64 + q * 4;
#pragma unroll
  for (int j = 0; j < 4; ++j) {
    int n = n0 + wn * 64 + j * 16 + fr;
    bool ok = (n < CKv);
    float cmax = -INFINITY;
#pragma unroll
    for (int i = 0; i < 4; ++i) {
#pragma unroll
      for (int r = 0; r < 4; ++r) {
        float v = acc[i][j][r];
        cmax = fmaxf(cmax, v);
        if (ok) Co[(size_t)(mbase + i * 16 + r) * CKv + n] = v;
      }
    }
    cmax = fmaxf(cmax, __shfl_xor(cmax, 16));
    cmax = fmaxf(cmax, __shfl_xor(cmax, 32));
    if (lane < 16 && ok)
      atomicMax(&iplU[(size_t)b_img * 1024 + n], fenc(cmax));
  }
}

// ---------------------------- finalize ipl + class_logits from atomic maxes
__global__ __launch_bounds__(256) void ipl_final_kernel(
    const unsigned int* __restrict__ iplU, const float* __restrict__ sa_w,
    float* __restrict__ out) {
  int b = blockIdx.x;
  int c = threadIdx.x;
  if (c >= Cv) return;
  float r[Kv];
#pragma unroll
  for (int k = 0; k < Kv; ++k) {
    r[k] = fdec(iplU[(size_t)b * 1024 + c * Kv + k]);
    out[OFF_IPL + (size_t)(b * Cv + c) * Kv + k] = r[k];
  }
  if (c < NCLS) {
    float w[Kv], wm = -INFINITY;
#pragma unroll
    for (int k = 0; k < Kv; ++k) { w[k] = sa_w[c * Kv + k]; wm = fmaxf(wm, w[k]); }
    float es = 0.f;
#pragma unroll
    for (int k = 0; k < Kv; ++k) { w[k] = expf(w[k] - wm); es += w[k]; }
    float cl = 0.f;
#pragma unroll
    for (int k = 0; k < Kv; ++k) cl += r[k] * (w[k] / es * (float)Kv);
    out[OFF_CL + b * NCLS + c] = cl / 0.2f;
  }
}

// ------------------- per-token pseudo label, softmax, argmax, threshold, A
__global__ __launch_bounds__(256) void assign_kernel(
    const float* __restrict__ logits, const int* __restrict__ labels,
    const int* __restrict__ sam, float* __restrict__ out,
    float* __restrict__ A_buf, int* __restrict__ tok_lab,
    int* __restrict__ present) {
  int n = blockIdx.x * 256 + threadIdx.x;
  if (n >= BNv) return;
  int b = n >> 10;
  int lab = (sam[n] == 1) ? labels[b] : NCLS;
  out[OFF_PSEUDO + n] = (float)lab;
  const float* p = logits + (size_t)n * CKv + lab * Kv;
  float L[Kv];
#pragma unroll
  for (int k = 0; k < Kv; ++k) L[k] = p[k];
  float mv = L[0];
  int idx = 0;
#pragma unroll
  for (int k = 1; k < Kv; ++k)
    if (L[k] > mv) { mv = L[k]; idx = k; }
  out[OFF_PART + n] = (float)(idx + lab * Kv);
  float e[Kv], s = 0.f;
#pragma unroll
  for (int k = 0; k < Kv; ++k) { e[k] = expf(L[k] - mv); s += e[k]; }
  float inv = 1.0f / s;
  float scale = (inv < 0.8f) ? 0.f : inv;
#pragma unroll
  for (int k = 0; k < Kv; ++k) A_buf[(size_t)n * Kv + k] = e[k] * scale;
  tok_lab[n] = lab;
  present[lab] = 1;
}

// --------------------------------------- per-class centroid accumulation
// grid (32 b, 3 d-chunks of 256, 8 n-chunks of 128)
__global__ __launch_bounds__(256) void accum_kernel(
    const float* __restrict__ raw, const float* __restrict__ inv_raw,
    const float* __restrict__ A_buf, const int* __restrict__ tok_lab,
    const int* __restrict__ labels, float* __restrict__ P_acc) {
  const int b = blockIdx.x;
  const int d = blockIdx.y * 256 + threadIdx.x;
  const int t0 = blockIdx.z * 128;
  __shared__ float As[128][Kv];
  __shared__ float Sc[128];
  __shared__ int   Ls[128];
  if (threadIdx.x < 128) {
    int n = b * Nv + t0 + threadIdx.x;
#pragma unroll
    for (int k = 0; k < Kv; ++k) As[threadIdx.x][k] = A_buf[(size_t)n * Kv + k];
    Ls[threadIdx.x] = tok_lab[n];
    Sc[threadIdx.x] = inv_raw[n];
  }
  __syncthreads();
  float accL[Kv] = {}, accB[Kv] = {};
#pragma unroll 4
  for (int t = 0; t < 128; ++t) {
    int n2 = b * Nv + t0 + t;
    float rv = raw[(size_t)n2 * Dv + d] * Sc[t];
    if (Ls[t] == NCLS) {
#pragma unroll
      for (int k = 0; k < Kv; ++k) accB[k] = fmaf(As[t][k], rv, accB[k]);
    } else {
#pragma unroll
      for (int k = 0; k < Kv; ++k) accL[k] = fmaf(As[t][k], rv, accL[k]);
    }
  }
  int lab = labels[b];
#pragma unroll
  for (int k = 0; k < Kv; ++k) atomicAdd(&P_acc[((size_t)lab * Kv + k) * Dv + d], accL[k]);
#pragma unroll
  for (int k = 0; k < Kv; ++k) atomicAdd(&P_acc[((size_t)NCLS * Kv + k) * Dv + d], accB[k]);
}

// ------------------------------------------------------------ EMA update
__global__ __launch_bounds__(256) void pnew_kernel(
    const float* __restrict__ proto, const float* __restrict__ P_acc,
    const int* __restrict__ present, float* __restrict__ out) {
  int i = blockIdx.x * 256 + threadIdx.x;
  if (i >= Cv * Kv * Dv) return;
  int c = i / (Kv * Dv);
  float p = proto[i];
  out[OFF_PNEW + i] = present[c] ? 0.999f * p + 0.001f * P_acc[i] : p;
}

// -------------------------------------------------------------- launcher
extern "C" void kernel_launch(void* const* d_in, const int* in_sizes, int n_in,
                              void* d_out, int out_size, void* d_ws, size_t ws_size,
                              hipStream_t stream) {
  const float* pt     = (const float*)d_in[0];
  const float* raw    = (const float*)d_in[1];
  const float* proto  = (const float*)d_in[2];
  const float* sa_w   = (const float*)d_in[3];
  const int*   labels = (const int*)d_in[4];
  const int*   sam    = (const int*)d_in[5];
  float* out = (float*)d_out;

  // ---- workspace layout ----
  float* A_buf   = (float*)d_ws;                           // 163840 f
  int*   tok_lab = (int*)(A_buf + (size_t)BNv * Kv);       // 32768 i
  float* P_acc   = (float*)(tok_lab + BNv);                // 771840 f
  int*   present = (int*)(P_acc + (size_t)Cv * Kv * Dv);   // 256 i (pad)
  unsigned int* iplU = (unsigned int*)(present + 256);     // 32768 u
  float* inv_raw = (float*)(iplU + BNv);                   // 32768 f
  unsigned short* Ah  = (unsigned short*)(inv_raw + BNv);  // 32768*768 us
  unsigned short* Bhl = Ah + (size_t)BNv * Dv;             // 1024*1536 us

  // zero region: P_acc + present + iplU (contiguous), fused into prep
  int nz = Cv * Kv * Dv + 256 + BNv;
  int ZB = (nz + 255) / 256;
  int prep_rows_blocks = (2 * BNv + 1024) / 4;

  prep_kernel<<<ZB + prep_rows_blocks, 256, 0, stream>>>(
      pt, raw, proto, Ah, Bhl, inv_raw, (int*)P_acc, nz, ZB);

  gemm_mfma_kernel<<<dim3(BNv / BM, 1024 / BN), 512, 0, stream>>>(
      Ah, Bhl, out + OFF_LOG, iplU);

  ipl_final_kernel<<<Bv, 256, 0, stream>>>(iplU, sa_w, out);

  assign_kernel<<<BNv / 256, 256, 0, stream>>>(
      out + OFF_LOG, labels, sam, out, A_buf, tok_lab, present);

  accum_kernel<<<dim3(Bv, Dv / 256, Nv / 128), 256, 0, stream>>>(
      raw, inv_raw, A_buf, tok_lab, labels, P_acc);

  pnew_kernel<<<(Cv * Kv * Dv + 255) / 256, 256, 0, stream>>>(
      proto, P_acc, present, out);
}

// Round 11
// 214.345 us; speedup vs baseline: 1.1828x; 1.1828x over previous
//
#include <hip/hip_runtime.h>
#include <math.h>

#define Bv   32
#define Nv   1024
#define Dv   768
#define Cv   201
#define Kv   5
#define CKv  1005
#define BNv  32768
#define NCLS 200

// output offsets (floats)
#define OFF_CL     0
#define OFF_IPL    6400
#define OFF_LOG    38560
#define OFF_PART   32970400
#define OFF_PNEW   33003168
#define OFF_PSEUDO 33775008

typedef short bf16x8 __attribute__((ext_vector_type(8)));
typedef float f32x4  __attribute__((ext_vector_type(4)));
typedef float f32x4u __attribute__((ext_vector_type(4), aligned(4)));
typedef __attribute__((address_space(1))) const unsigned int g_u32;
typedef __attribute__((address_space(3))) unsigned int l_u32;

__device__ inline unsigned short f2bf(float f) {
  unsigned u = __float_as_uint(f);
  u += 0x7fffu + ((u >> 16) & 1u);     // RNE
  return (unsigned short)(u >> 16);
}
__device__ inline float bf2f(unsigned short h) {
  return __uint_as_float(((unsigned)h) << 16);
}
// order-preserving float<->uint for atomicMax
__device__ inline unsigned fenc(float f) {
  unsigned u = __float_as_uint(f);
  return u ^ (((unsigned)((int)u >> 31)) | 0x80000000u);
}
__device__ inline float fdec(unsigned u) {
  unsigned bits = (u & 0x80000000u) ? (u ^ 0x80000000u) : ~u;
  return __uint_as_float(bits);
}

// ---------------- fused: zero (leading blocks) + row norms + bf16 split
__global__ __launch_bounds__(256) void prep_kernel(
    const float* __restrict__ pt, const float* __restrict__ raw,
    const float* __restrict__ proto,
    unsigned short* __restrict__ Ah, unsigned short* __restrict__ Bhl,
    float* __restrict__ inv_raw, int* __restrict__ zbuf, int zn, int ZB) {
  if ((int)blockIdx.x < ZB) {
    int i = blockIdx.x * 256 + threadIdx.x;
    if (i < zn) zbuf[i] = 0;
    return;
  }
  int row = (blockIdx.x - ZB) * 4 + (threadIdx.x >> 6);
  int l   = threadIdx.x & 63;

  if (row < BNv) {                       // ---- A: hi-only
    const float* src = pt + (size_t)row * Dv;
    unsigned short* dst = Ah + (size_t)row * Dv;
    float4 v[3];
    float s = 0.f;
#pragma unroll
    for (int i = 0; i < 3; ++i) {
      v[i] = reinterpret_cast<const float4*>(src)[i * 64 + l];
      s += v[i].x * v[i].x + v[i].y * v[i].y + v[i].z * v[i].z + v[i].w * v[i].w;
    }
#pragma unroll
    for (int off = 32; off > 0; off >>= 1) s += __shfl_xor(s, off);
    float inv = 1.0f / fmaxf(sqrtf(s), 1e-12f);
#pragma unroll
    for (int i = 0; i < 3; ++i) {
      float a[4] = {v[i].x * inv, v[i].y * inv, v[i].z * inv, v[i].w * inv};
      *reinterpret_cast<ushort4*>(dst + i * 256 + 4 * l) =
          make_ushort4(f2bf(a[0]), f2bf(a[1]), f2bf(a[2]), f2bf(a[3]));
    }
    return;
  }
  if (row < BNv + 1024) {                // ---- B: hi|lo interleaved
    int rp = row - BNv;
    unsigned short* dst = Bhl + (size_t)rp * 1536;
    if (rp >= CKv) {                     // zero-fill pad rows
      ushort4 z = make_ushort4(0, 0, 0, 0);
#pragma unroll
      for (int i = 0; i < 3; ++i) {
        int db = 8 * i + (l >> 3);
        int base = db * 64 + 4 * (l & 7);
        *reinterpret_cast<ushort4*>(dst + base)      = z;
        *reinterpret_cast<ushort4*>(dst + base + 32) = z;
      }
      return;
    }
    const float* src = proto + (size_t)rp * Dv;
    float4 v[3];
    float s = 0.f;
#pragma unroll
    for (int i = 0; i < 3; ++i) {
      v[i] = reinterpret_cast<const float4*>(src)[i * 64 + l];
      s += v[i].x * v[i].x + v[i].y * v[i].y + v[i].z * v[i].z + v[i].w * v[i].w;
    }
#pragma unroll
    for (int off = 32; off > 0; off >>= 1) s += __shfl_xor(s, off);
    float inv = 1.0f / fmaxf(sqrtf(s), 1e-12f);
#pragma unroll
    for (int i = 0; i < 3; ++i) {
      float a[4] = {v[i].x * inv, v[i].y * inv, v[i].z * inv, v[i].w * inv};
      unsigned short hh[4], ll[4];
#pragma unroll
      for (int t = 0; t < 4; ++t) {
        hh[t] = f2bf(a[t]);
        ll[t] = f2bf(a[t] - bf2f(hh[t]));
      }
      int db = 8 * i + (l >> 3);
      int base = db * 64 + 4 * (l & 7);
      *reinterpret_cast<ushort4*>(dst + base)      = make_ushort4(hh[0], hh[1], hh[2], hh[3]);
      *reinterpret_cast<ushort4*>(dst + base + 32) = make_ushort4(ll[0], ll[1], ll[2], ll[3]);
    }
    return;
  }
  if (row < 2 * BNv + 1024) {            // ---- raw: norm only
    int rr = row - BNv - 1024;
    const float* src = raw + (size_t)rr * Dv;
    float s = 0.f;
#pragma unroll
    for (int i = 0; i < 3; ++i) {
      float4 v = reinterpret_cast<const float4*>(src)[i * 64 + l];
      s += v.x * v.x + v.y * v.y + v.z * v.z + v.w * v.w;
    }
#pragma unroll
    for (int off = 32; off > 0; off >>= 1) s += __shfl_xor(s, off);
    if (l == 0) inv_raw[rr] = 1.0f / fmaxf(sqrtf(s), 1e-12f);
  }
}

// ------------------------------------------------- MFMA 2-pass split GEMM
// logits[m][n] = dot(a_hi[m,:], b_hi[n,:]+b_lo[n,:]); fused col-max -> iplU
// BM=256 x BN=128, 512 thr / 8 waves (4M x 2N), BK=32 (24 tiles), dbuf LDS.
// K-loop: 4 fine phases per tile, counted vmcnt(4), setprio around MFMA.
// Epilogue: LDS repack (reusing K-loop LDS) -> 512B-contiguous row stores
// (R10 per-fragment stores gave 1.67x HBM write amplification, stride
// 4020B % 64 = 52 => every 64B fragment straddles sectors).
#define BM 256
#define BN 128
__global__ __launch_bounds__(512) void gemm_mfma_kernel(
    const unsigned short* __restrict__ Ah, const unsigned short* __restrict__ Bhl,
    float* __restrict__ Co, unsigned int* __restrict__ iplU) {
  __shared__ __align__(16) unsigned char smem[65536];
#define LA(b) ((unsigned short (*)[32])(smem + (b) * 16384))
#define LB(b) ((unsigned short (*)[64])(smem + 32768 + (b) * 16384))
  const int tid  = threadIdx.x;
  const int wid  = tid >> 6;
  const int lane = tid & 63;
  const int wm = wid >> 1, wn = wid & 1;
  const int m0 = blockIdx.x * BM, n0 = blockIdx.y * BN;
  const int fr = lane & 15;
  const int q  = lane >> 4;

  f32x4 acc[4][4];
#pragma unroll
  for (int i = 0; i < 4; ++i)
#pragma unroll
    for (int j = 0; j < 4; ++j)
#pragma unroll
      for (int r = 0; r < 4; ++r) acc[i][j][r] = 0.f;

  // staging source pointers (swizzled global source, linear LDS dest).
  const int raA = wid * 16 + (lane >> 2);            // 0..127
  const int saA = (lane & 3) ^ ((raA >> 1) & 3);     // +128 preserves (row>>1)&3
  const unsigned short* srcA0 = Ah + (size_t)(m0 + raA) * Dv + saA * 8;
  const unsigned short* srcA1 = Ah + (size_t)(m0 + 128 + raA) * Dv + saA * 8;
  const int rbB = wid * 8 + (lane >> 3);             // 0..63
  const int sbB = (lane & 7) ^ (rbB & 7);            // +64 preserves row&7
  const unsigned short* srcB0 = Bhl + (size_t)(n0 + rbB) * 1536 + sbB * 8;
  const unsigned short* srcB1 = Bhl + (size_t)(n0 + 64 + rbB) * 1536 + sbB * 8;

#define STG_A0(buf, t) __builtin_amdgcn_global_load_lds((g_u32*)(srcA0 + (t) * 32), \
    (l_u32*)&LA(buf)[wid * 16][0], 16, 0, 0)
#define STG_A1(buf, t) __builtin_amdgcn_global_load_lds((g_u32*)(srcA1 + (t) * 32), \
    (l_u32*)&LA(buf)[128 + wid * 16][0], 16, 0, 0)
#define STG_B0(buf, t) __builtin_amdgcn_global_load_lds((g_u32*)(srcB0 + (t) * 64), \
    (l_u32*)&LB(buf)[wid * 8][0], 16, 0, 0)
#define STG_B1(buf, t) __builtin_amdgcn_global_load_lds((g_u32*)(srcB1 + (t) * 64), \
    (l_u32*)&LB(buf)[64 + wid * 8][0], 16, 0, 0)

  const int slotA = (q ^ ((fr >> 1) & 3)) * 8;       // const per lane
  const int shB   = (q ^ (fr & 7)) * 8;
  const int slB   = ((q + 4) ^ (fr & 7)) * 8;

  // prologue: tile 0 into buf 0 (4 loads/wave in flight)
  STG_A0(0, 0); STG_A1(0, 0); STG_B0(0, 0); STG_B1(0, 0);

#pragma unroll 2
  for (int t = 0; t < 24; ++t) {
    const int cur = t & 1;
    // issue all 4 next-tile loads, then counted wait (they stay in flight)
    if (t < 23) {
      STG_A0(cur ^ 1, t + 1); STG_A1(cur ^ 1, t + 1);
      STG_B0(cur ^ 1, t + 1); STG_B1(cur ^ 1, t + 1);
      asm volatile("s_waitcnt vmcnt(4)" ::: "memory");
    } else {
      asm volatile("s_waitcnt vmcnt(0)" ::: "memory");
    }
    __builtin_amdgcn_s_barrier();            // all waves' tile-t stage landed
    __builtin_amdgcn_sched_barrier(0);       // pin ds_reads below barrier

    bf16x8 a[4];
#pragma unroll
    for (int j = 0; j < 4; ++j) {
      // ---- phase j: ds-load subtile, fence, MFMA cluster, barrier ----
      if (j == 0) {
#pragma unroll
        for (int i = 0; i < 4; ++i)
          a[i] = *reinterpret_cast<const bf16x8*>(&LA(cur)[wm * 64 + i * 16 + fr][slotA]);
      }
      const unsigned short* pb = &LB(cur)[wn * 64 + j * 16 + fr][0];
      bf16x8 bh = *reinterpret_cast<const bf16x8*>(pb + shB);
      bf16x8 bl = *reinterpret_cast<const bf16x8*>(pb + slB);
      asm volatile("s_waitcnt lgkmcnt(0)" ::: "memory");
      __builtin_amdgcn_sched_barrier(0);
      __builtin_amdgcn_s_setprio(1);
#pragma unroll
      for (int i = 0; i < 4; ++i) {
        acc[i][j] = __builtin_amdgcn_mfma_f32_16x16x32_bf16(a[i], bh, acc[i][j], 0, 0, 0);
        acc[i][j] = __builtin_amdgcn_mfma_f32_16x16x32_bf16(a[i], bl, acc[i][j], 0, 0, 0);
      }
      __builtin_amdgcn_s_setprio(0);
      __builtin_amdgcn_sched_barrier(0);
      __builtin_amdgcn_s_barrier();          // phase boundary (wave lockstep)
      __builtin_amdgcn_sched_barrier(0);
    }
  }
#undef STG_A0
#undef STG_A1
#undef STG_B0
#undef STG_B1

  // ---- column-max + atomics (register-only, before LDS reuse) ----
  const int b_img = m0 >> 10;
#pragma unroll
  for (int j = 0; j < 4; ++j) {
    int n = n0 + wn * 64 + j * 16 + fr;
    bool ok = (n < CKv);
    float cmax = -INFINITY;
#pragma unroll
    for (int i = 0; i < 4; ++i)
#pragma unroll
      for (int r = 0; r < 4; ++r) cmax = fmaxf(cmax, acc[i][j][r]);
    cmax = fmaxf(cmax, __shfl_xor(cmax, 16));
    cmax = fmaxf(cmax, __shfl_xor(cmax, 32));
    if (lane < 16 && ok)
      atomicMax(&iplU[(size_t)b_img * 1024 + n], fenc(cmax));
  }

  // ---- repack through LDS -> contiguous 512B row stores ----
  float (*ebuf)[132] = (float (*)[132])smem;   // 64 rows x 132 (pad) floats
  const int r2 = lane >> 5;                    // 0/1: row within pair
  const int cl = (lane & 31) * 4;              // col (floats)
#pragma unroll
  for (int p = 0; p < 4; ++p) {
    __syncthreads();                           // WAR vs previous pass readers
    if (wm == p) {
#pragma unroll
      for (int i = 0; i < 4; ++i)
#pragma unroll
        for (int j = 0; j < 4; ++j)
#pragma unroll
          for (int r = 0; r < 4; ++r)
            ebuf[i * 16 + q * 4 + r][wn * 64 + j * 16 + fr] = acc[i][j][r];
    }
    __syncthreads();
#pragma unroll
    for (int rr = 0; rr < 8; rr += 2) {
      int row = wid * 8 + rr + r2;
      f32x4 v = *reinterpret_cast<const f32x4*>(&ebuf[row][cl]);
      int gc = n0 + cl;
      size_t base = (size_t)(m0 + p * 64 + row) * CKv + gc;
      if (gc + 3 < CKv) {
        *reinterpret_cast<f32x4u*>(&Co[base]) = v;
      } else {
#pragma unroll
        for (int e = 0; e < 4; ++e)
          if (gc + e < CKv) Co[base + e] = v[e];
      }
    }
  }
#undef LA
#undef LB
}

// ---------- fused: per-token assign (+A) and ipl/class_logits finalize
__global__ __launch_bounds__(256) void assign_ipl_kernel(
    const float* __restrict__ logits, const int* __restrict__ labels,
    const int* __restrict__ sam, float* __restrict__ out,
    float* __restrict__ A_buf, int* __restrict__ tok_lab,
    int* __restrict__ present,
    const unsigned int* __restrict__ iplU, const float* __restrict__ sa_w) {
  if ((int)blockIdx.x >= BNv / 256) {
    // ---- ipl finalize: one block per image ----
    int b = blockIdx.x - BNv / 256;
    int c = threadIdx.x;
    if (c >= Cv) return;
    float r[Kv];
#pragma unroll
    for (int k = 0; k < Kv; ++k) {
      r[k] = fdec(iplU[(size_t)b * 1024 + c * Kv + k]);
      out[OFF_IPL + (size_t)(b * Cv + c) * Kv + k] = r[k];
    }
    if (c < NCLS) {
      float w[Kv], wm = -INFINITY;
#pragma unroll
      for (int k = 0; k < Kv; ++k) { w[k] = sa_w[c * Kv + k]; wm = fmaxf(wm, w[k]); }
      float es = 0.f;
#pragma unroll
      for (int k = 0; k < Kv; ++k) { w[k] = expf(w[k] - wm); es += w[k]; }
      float cl = 0.f;
#pragma unroll
      for (int k = 0; k < Kv; ++k) cl += r[k] * (w[k] / es * (float)Kv);
      out[OFF_CL + b * NCLS + c] = cl / 0.2f;
    }
    return;
  }
  int n = blockIdx.x * 256 + threadIdx.x;
  int b = n >> 10;
  int lab = (sam[n] == 1) ? labels[b] : NCLS;
  out[OFF_PSEUDO + n] = (float)lab;
  const float* p = logits + (size_t)n * CKv + lab * Kv;
  float L[Kv];
#pragma unroll
  for (int k = 0; k < Kv; ++k) L[k] = p[k];
  float mv = L[0];
  int idx = 0;
#pragma unroll
  for (int k = 1; k < Kv; ++k)
    if (L[k] > mv) { mv = L[k]; idx = k; }
  out[OFF_PART + n] = (float)(idx + lab * Kv);
  float e[Kv], s = 0.f;
#pragma unroll
  for (int k = 0; k < Kv; ++k) { e[k] = expf(L[k] - mv); s += e[k]; }
  float inv = 1.0f / s;
  float scale = (inv < 0.8f) ? 0.f : inv;
#pragma unroll
  for (int k = 0; k < Kv; ++k) A_buf[(size_t)n * Kv + k] = e[k] * scale;
  tok_lab[n] = lab;
  present[lab] = 1;
}

// --------------------------------------- per-class centroid accumulation
// grid (32 b, 3 d-chunks of 256, 8 n-chunks of 128)
__global__ __launch_bounds__(256) void accum_kernel(
    const float* __restrict__ raw, const float* __restrict__ inv_raw,
    const float* __restrict__ A_buf, const int* __restrict__ tok_lab,
    const int* __restrict__ labels, float* __restrict__ P_acc) {
  const int b = blockIdx.x;
  const int d = blockIdx.y * 256 + threadIdx.x;
  const int t0 = blockIdx.z * 128;
  __shared__ float As[128][Kv];
  __shared__ float Sc[128];
  __shared__ int   Ls[128];
  if (threadIdx.x < 128) {
    int n = b * Nv + t0 + threadIdx.x;
#pragma unroll
    for (int k = 0; k < Kv; ++k) As[threadIdx.x][k] = A_buf[(size_t)n * Kv + k];
    Ls[threadIdx.x] = tok_lab[n];
    Sc[threadIdx.x] = inv_raw[n];
  }
  __syncthreads();
  float accL[Kv] = {}, accB[Kv] = {};
#pragma unroll 4
  for (int t = 0; t < 128; ++t) {
    int n2 = b * Nv + t0 + t;
    float rv = raw[(size_t)n2 * Dv + d] * Sc[t];
    if (Ls[t] == NCLS) {
#pragma unroll
      for (int k = 0; k < Kv; ++k) accB[k] = fmaf(As[t][k], rv, accB[k]);
    } else {
#pragma unroll
      for (int k = 0; k < Kv; ++k) accL[k] = fmaf(As[t][k], rv, accL[k]);
    }
  }
  int lab = labels[b];
#pragma unroll
  for (int k = 0; k < Kv; ++k) atomicAdd(&P_acc[((size_t)lab * Kv + k) * Dv + d], accL[k]);
#pragma unroll
  for (int k = 0; k < Kv; ++k) atomicAdd(&P_acc[((size_t)NCLS * Kv + k) * Dv + d], accB[k]);
}

// ------------------------------------------------------------ EMA update
__global__ __launch_bounds__(256) void pnew_kernel(
    const float* __restrict__ proto, const float* __restrict__ P_acc,
    const int* __restrict__ present, float* __restrict__ out) {
  int i = blockIdx.x * 256 + threadIdx.x;
  if (i >= Cv * Kv * Dv) return;
  int c = i / (Kv * Dv);
  float p = proto[i];
  out[OFF_PNEW + i] = present[c] ? 0.999f * p + 0.001f * P_acc[i] : p;
}

// -------------------------------------------------------------- launcher
extern "C" void kernel_launch(void* const* d_in, const int* in_sizes, int n_in,
                              void* d_out, int out_size, void* d_ws, size_t ws_size,
                              hipStream_t stream) {
  const float* pt     = (const float*)d_in[0];
  const float* raw    = (const float*)d_in[1];
  const float* proto  = (const float*)d_in[2];
  const float* sa_w   = (const float*)d_in[3];
  const int*   labels = (const int*)d_in[4];
  const int*   sam    = (const int*)d_in[5];
  float* out = (float*)d_out;

  // ---- workspace layout ----
  float* A_buf   = (float*)d_ws;                           // 163840 f
  int*   tok_lab = (int*)(A_buf + (size_t)BNv * Kv);       // 32768 i
  float* P_acc   = (float*)(tok_lab + BNv);                // 771840 f
  int*   present = (int*)(P_acc + (size_t)Cv * Kv * Dv);   // 256 i (pad)
  unsigned int* iplU = (unsigned int*)(present + 256);     // 32768 u
  float* inv_raw = (float*)(iplU + BNv);                   // 32768 f
  unsigned short* Ah  = (unsigned short*)(inv_raw + BNv);  // 32768*768 us
  unsigned short* Bhl = Ah + (size_t)BNv * Dv;             // 1024*1536 us

  // zero region: P_acc + present + iplU (contiguous), fused into prep
  int nz = Cv * Kv * Dv + 256 + BNv;
  int ZB = (nz + 255) / 256;
  int prep_rows_blocks = (2 * BNv + 1024) / 4;

  prep_kernel<<<ZB + prep_rows_blocks, 256, 0, stream>>>(
      pt, raw, proto, Ah, Bhl, inv_raw, (int*)P_acc, nz, ZB);

  gemm_mfma_kernel<<<dim3(BNv / BM, 1024 / BN), 512, 0, stream>>>(
      Ah, Bhl, out + OFF_LOG, iplU);

  assign_ipl_kernel<<<BNv / 256 + Bv, 256, 0, stream>>>(
      out + OFF_LOG, labels, sam, out, A_buf, tok_lab, present, iplU, sa_w);

  accum_kernel<<<dim3(Bv, Dv / 256, Nv / 128), 256, 0, stream>>>(
      raw, inv_raw, A_buf, tok_lab, labels, P_acc);

  pnew_kernel<<<(Cv * Kv * Dv + 255) / 256, 256, 0, stream>>>(
      proto, P_acc, present, out);
}